// Round 10
// baseline (105.047 us; speedup 1.0000x reference)
//
#include <hip/hip_runtime.h>

// TT Q-gather — R8 structure (proven best) + tiled table build.
//
//   v = V01[s0][s1][:]      (bf16 fold of G0*G1, 1MB)
//   for k=2..5: v = v @ Gk[:,sk,:]   (bf16 transposed matrix-contiguous, 32KB each)
//   q = v . U67[s6][a7][:]  (bf16 fold of G6*G7, 1MB)
//
// Gather kernel is TA address-serialization bound: 34 divergent wave-instrs
// per element ~= 14.5us floor (measured ~16us). R9 falsified further folding
// (16MB tables break 4MB/XCD L2 residency). This round trims build_tables:
// 8-row tiling reuses each thread's G1/G6 slice across 8 outputs ->
// G1 demand 16MB -> 2MB, 544 -> 96 blocks.
//
// ws layout (ushort units):
//   V01  @ 0       : [s0][s1][8]   (1 MB)
//   U67  @ 524288  : [s6][s7][8]   (1 MB)
//   Gt_k @ 1048576 + k*16384 : [n][r][s] 256*64 (32 KB), k=0..3 -> G2..G5

#define NN 256
#define RR 8
#define NR 2048   // N * R
#define U67_OFF 524288
#define GT_OFF  1048576

__device__ __forceinline__ unsigned short f2bf_rne(float f) {
    unsigned int u = __float_as_uint(f);
    u += 0x7FFFu + ((u >> 16) & 1u);
    return (unsigned short)(u >> 16);
}

__device__ __forceinline__ uint4 pack8bf(const float* a) {
    return make_uint4(
        f2bf_rne(a[0]) | ((unsigned int)f2bf_rne(a[1]) << 16),
        f2bf_rne(a[2]) | ((unsigned int)f2bf_rne(a[3]) << 16),
        f2bf_rne(a[4]) | ((unsigned int)f2bf_rne(a[5]) << 16),
        f2bf_rne(a[6]) | ((unsigned int)f2bf_rne(a[7]) << 16));
}

// 96 blocks x 256 threads:
//   bid 0..31  -> V01, 8 n0-rows per block (thread t = n1, G1 slice in regs)
//   bid 32..63 -> U67, 8 n6-rows per block (thread t = n7)
//   bid 64..95 -> transpose G2..G5 (8 blocks per core)
__global__ __launch_bounds__(256) void build_tables(
    const float* __restrict__ G0, const float* __restrict__ G1,
    const float* __restrict__ G2, const float* __restrict__ G3,
    const float* __restrict__ G4, const float* __restrict__ G5,
    const float* __restrict__ G6, const float* __restrict__ G7,
    unsigned short* __restrict__ wsb) {
    const int t = threadIdx.x;
    const int bid = blockIdx.x;

    if (bid < 32) {
        // V01[n0][n1][s] = sum_r G0[n0,r] * G1[r,n1,s], n0 in 8-row tile
        const int n0b = bid * 8;
        const int n1 = t;
        float g1v[RR][RR];   // this thread's G1[r][n1][:] slice (64 regs)
#pragma unroll
        for (int r = 0; r < RR; ++r) {
            const float4* p = (const float4*)(G1 + r * NR + n1 * RR);
            float4 x = p[0], y = p[1];
            g1v[r][0] = x.x; g1v[r][1] = x.y; g1v[r][2] = x.z; g1v[r][3] = x.w;
            g1v[r][4] = y.x; g1v[r][5] = y.y; g1v[r][6] = y.z; g1v[r][7] = y.w;
        }
#pragma unroll
        for (int i = 0; i < 8; ++i) {
            const int n0 = n0b + i;
            float acc[RR] = {0.f,0.f,0.f,0.f,0.f,0.f,0.f,0.f};
#pragma unroll
            for (int r = 0; r < RR; ++r) {
                float ar = G0[n0 * RR + r];   // wave-uniform
#pragma unroll
                for (int s = 0; s < RR; ++s) acc[s] += ar * g1v[r][s];
            }
            *(uint4*)(wsb + n0 * 2048 + n1 * 8) = pack8bf(acc);
        }
    } else if (bid < 64) {
        // U67[n6][n7][r] = sum_s G6[r,n6,s] * G7[s,n7], n6 in 8-row tile
        const int n6b = (bid - 32) * 8;
        const int n7 = t;
        float g7v[RR];
#pragma unroll
        for (int s = 0; s < RR; ++s) g7v[s] = G7[s * NN + n7];
#pragma unroll
        for (int i = 0; i < 8; ++i) {
            const int n6 = n6b + i;
            float u[RR];
#pragma unroll
            for (int r = 0; r < RR; ++r) {
                float acc = 0.f;
#pragma unroll
                for (int s = 0; s < RR; ++s)
                    acc += G6[r * NR + n6 * RR + s] * g7v[s];   // uniform
                u[r] = acc;
            }
            *(uint4*)(wsb + U67_OFF + n6 * 2048 + n7 * 8) = pack8bf(u);
        }
    } else {
        // transpose G2..G5 -> Gt[n][r][s] bf16 (matrix-contiguous 128B)
        const int q = bid - 64;            // 0..31
        const int k = q >> 3;              // 0..3 -> G2..G5
        const int chunk = q & 7;
        const float* __restrict__ Gk =
            (k == 0) ? G2 : (k == 1) ? G3 : (k == 2) ? G4 : G5;
        const int n = chunk * 32 + (t >> 3);
        const int r = t & 7;
        const float4* src = (const float4*)(Gk + r * NR + n * RR);
        float4 x = src[0], y = src[1];
        float a[8] = {x.x, x.y, x.z, x.w, y.x, y.y, y.z, y.w};
        *(uint4*)(wsb + GT_OFF + k * 16384 + n * 64 + r * 8) = pack8bf(a);
    }
}

#define BF2F_LO(u) __uint_as_float((u) << 16)
#define BF2F_HI(u) __uint_as_float((u) & 0xFFFF0000u)

// one chain stage: v = v @ M, M = 8x8 bf16 matrix contiguous at mp
#define BSTAGE(koff, nidx)                                                  \
    do {                                                                    \
        const uint4* mp =                                                   \
            (const uint4*)(wsb + GT_OFF + (koff)*16384 + (nidx)*64);        \
        float nv0 = 0.f, nv1 = 0.f, nv2 = 0.f, nv3 = 0.f;                   \
        float nv4 = 0.f, nv5 = 0.f, nv6 = 0.f, nv7 = 0.f;                   \
        _Pragma("unroll") for (int r = 0; r < 8; ++r) {                     \
            uint4 u = mp[r];                                                \
            float vr = v[r];                                                \
            nv0 += vr * BF2F_LO(u.x); nv1 += vr * BF2F_HI(u.x);             \
            nv2 += vr * BF2F_LO(u.y); nv3 += vr * BF2F_HI(u.y);             \
            nv4 += vr * BF2F_LO(u.z); nv5 += vr * BF2F_HI(u.z);             \
            nv6 += vr * BF2F_LO(u.w); nv7 += vr * BF2F_HI(u.w);             \
        }                                                                   \
        v[0] = nv0; v[1] = nv1; v[2] = nv2; v[3] = nv3;                     \
        v[4] = nv4; v[5] = nv5; v[6] = nv6; v[7] = nv7;                     \
    } while (0)

__global__ __launch_bounds__(256) void tt_gather(
    const unsigned short* __restrict__ wsb,
    const int* __restrict__ states, const int* __restrict__ actions,
    float* __restrict__ out, int B) {
    __shared__ int ibuf[NN * 7];   // 7 KB: this block's 256 state rows

    const int t = threadIdx.x;
    const int b = blockIdx.x * 256 + t;

    // coalesced staging of states rows
    {
        const int* gsrc = states + (size_t)blockIdx.x * 256 * 7;
        const int lim = B * 7 - blockIdx.x * 256 * 7;
#pragma unroll
        for (int k = 0; k < 7; ++k) {
            int j = t + (k << 8);
            if (j < lim) ibuf[j] = gsrc[j];
        }
    }
    __syncthreads();

    const bool active = (b < B);
    const int* row = ibuf + t * 7;            // stride 7: conflict-free
    const int s0 = row[0] & 255;
    const int s1 = row[1] & 255;
    const int s2 = row[2] & 255;
    const int s3 = row[3] & 255;
    const int s4 = row[4] & 255;
    const int s5 = row[5] & 255;
    const int s6 = row[6] & 255;
    const int a7 = actions[active ? b : 0] & 255;

    float v[8];
    {
        uint4 u = *(const uint4*)(wsb + s0 * 2048 + s1 * 8);
        v[0] = BF2F_LO(u.x); v[1] = BF2F_HI(u.x);
        v[2] = BF2F_LO(u.y); v[3] = BF2F_HI(u.y);
        v[4] = BF2F_LO(u.z); v[5] = BF2F_HI(u.z);
        v[6] = BF2F_LO(u.w); v[7] = BF2F_HI(u.w);
    }

    BSTAGE(0, s2);
    BSTAGE(1, s3);
    BSTAGE(2, s4);
    BSTAGE(3, s5);

    float q;
    {
        uint4 u = *(const uint4*)(wsb + U67_OFF + s6 * 2048 + a7 * 8);
        q = v[0] * BF2F_LO(u.x) + v[1] * BF2F_HI(u.x)
          + v[2] * BF2F_LO(u.y) + v[3] * BF2F_HI(u.y)
          + v[4] * BF2F_LO(u.z) + v[5] * BF2F_HI(u.z)
          + v[6] * BF2F_LO(u.w) + v[7] * BF2F_HI(u.w);
    }
    if (active) out[b] = q;
}

extern "C" void kernel_launch(void* const* d_in, const int* in_sizes, int n_in,
                              void* d_out, int out_size, void* d_ws, size_t ws_size,
                              hipStream_t stream) {
    const float* G0 = (const float*)d_in[0];
    const float* G1 = (const float*)d_in[1];
    const float* G2 = (const float*)d_in[2];
    const float* G3 = (const float*)d_in[3];
    const float* G4 = (const float*)d_in[4];
    const float* G5 = (const float*)d_in[5];
    const float* G6 = (const float*)d_in[6];
    const float* G7 = (const float*)d_in[7];
    const int* states  = (const int*)d_in[8];
    const int* actions = (const int*)d_in[9];
    float* out = (float*)d_out;
    int B = in_sizes[9];

    unsigned short* wsb = (unsigned short*)d_ws;   // ~2.1 MB used

    hipLaunchKernelGGL(build_tables, dim3(96), dim3(256), 0, stream,
                       G0, G1, G2, G3, G4, G5, G6, G7, wsb);

    hipLaunchKernelGGL(tt_gather, dim3((B + 255) / 256), dim3(256), 0, stream,
                       wsb, states, actions, out, B);
}